// Round 13
// baseline (568.083 us; speedup 1.0000x reference)
//
#include <hip/hip_runtime.h>
#include <hip/hip_cooperative_groups.h>

namespace cg = cooperative_groups;

#define N_NODES 50000
#define N_EDGES 800000
#define IN_CH   64
#define OUT_CH  128
#define FEAT    192                          // IN_CH * 3 powers
#define NBK     ((N_NODES + 255) / 256)      // 196 dst-buckets of 256 nodes
#define EPB     4096                         // edges per partition chunk
#define NPB     ((N_EDGES + EPB - 1) / EPB)  // 196 edge-chunks
#define N_TILES (N_NODES / 16)               // 3125 wave-tiles for GEMM
#define CAST_TASKS  ((N_NODES * IN_CH / 8 + 255) / 256)   // 1563
#define WFRAG_TASKS ((FEAT * OUT_CH + 255) / 256)         // 96
#define GATHER_TASKS ((N_NODES * 64) / 256)               // 12500 (exact)
#define GEMM_TASKS  ((N_TILES + 3) / 4)                   // 782
#define GRID    512                          // 2 blocks/CU co-resident

typedef __attribute__((ext_vector_type(8))) short short8;  // 8 bf16 (4 VGPRs)
typedef __attribute__((ext_vector_type(4))) float f32x4;

static __device__ __forceinline__ unsigned short f2bf(float f) {
  unsigned int u = __float_as_uint(f);
  u += 0x7FFFu + ((u >> 16) & 1u);
  return (unsigned short)(u >> 16);
}
static __device__ __forceinline__ float bf2f(unsigned int s) {
  return __uint_as_float(s << 16);
}

// ===========================================================================
// Phase bodies as __device__ helpers — shared verbatim by the fused
// cooperative kernel and the standalone fallback kernels (round-11-proven).
// ===========================================================================

static __device__ __forceinline__ void dev_hist(int b, int tid, int* lh,
    const int* __restrict__ ei, int* __restrict__ hist_t) {
  for (int i = tid; i < NBK; i += 256) lh[i] = 0;
  __syncthreads();
  const int e0 = b * EPB;
  const int e1 = (e0 + EPB < N_EDGES) ? e0 + EPB : N_EDGES;
  for (int e = e0 + tid; e < e1; e += 256)
    atomicAdd(&lh[((unsigned)ei[N_EDGES + e]) >> 8], 1);
  __syncthreads();
  for (int k = tid; k < NBK; k += 256) hist_t[k * NPB + b] = lh[k];
  __syncthreads();
}

static __device__ __forceinline__ void dev_cast(int i,
    const float* __restrict__ x, unsigned short* __restrict__ xb) {
  if (i >= (N_NODES * IN_CH) / 8) return;
  const float4 a = reinterpret_cast<const float4*>(x)[i * 2];
  const float4 c = reinterpret_cast<const float4*>(x)[i * 2 + 1];
  union { unsigned u[4]; uint4 v; } o;
  o.u[0] = (unsigned)f2bf(a.x) | ((unsigned)f2bf(a.y) << 16);
  o.u[1] = (unsigned)f2bf(a.z) | ((unsigned)f2bf(a.w) << 16);
  o.u[2] = (unsigned)f2bf(c.x) | ((unsigned)f2bf(c.y) << 16);
  o.u[3] = (unsigned)f2bf(c.z) | ((unsigned)f2bf(c.w) << 16);
  reinterpret_cast<uint4*>(xb)[i] = o.v;
}

static __device__ __forceinline__ void dev_wfrag(int i,
    const float* __restrict__ W, unsigned short* __restrict__ Wf) {
  if (i >= FEAT * OUT_CH) return;
  const int j = i & 7;
  const int l = (i >> 3) & 63;
  const int nt = (i >> 9) & 7;
  const int kk = i >> 12;
  const int o = nt * 16 + (l & 15);
  const int k = kk * 32 + (l >> 4) * 8 + j;
  Wf[i] = f2bf(W[o * FEAT + k]);
}

static __device__ __forceinline__ void dev_scan(int k, int tid, int* s,
    const int* __restrict__ hist_t, int* __restrict__ offs_t,
    int* __restrict__ total) {
  const int v = (tid < NPB) ? hist_t[k * NPB + tid] : 0;
  s[tid] = v;
  __syncthreads();
  for (int off = 1; off < 256; off <<= 1) {
    const int u = (tid >= off) ? s[tid - off] : 0;
    __syncthreads();
    s[tid] += u;
    __syncthreads();
  }
  if (tid < NPB) offs_t[k * NPB + tid] = s[tid] - v;  // exclusive
  if (tid == 255) total[k] = s[255];
  __syncthreads();
}

static __device__ __forceinline__ void dev_fill(int b, int tid, int* s,
    int* cur, const int* __restrict__ ei, const int* __restrict__ total,
    const int* __restrict__ offs_t, unsigned* __restrict__ pairs) {
  const int v = (tid < NBK) ? total[tid] : 0;
  s[tid] = v;
  __syncthreads();
  for (int off = 1; off < 256; off <<= 1) {
    const int u = (tid >= off) ? s[tid - off] : 0;
    __syncthreads();
    s[tid] += u;
    __syncthreads();
  }
  if (tid < NBK) cur[tid] = (s[tid] - v) + offs_t[tid * NPB + b];
  __syncthreads();
  const int e0 = b * EPB;
  const int e1 = (e0 + EPB < N_EDGES) ? e0 + EPB : N_EDGES;
  for (int e = e0 + tid; e < e1; e += 256) {
    const unsigned sv = (unsigned)ei[e];
    const unsigned d = (unsigned)ei[N_EDGES + e];
    const int pos = atomicAdd(&cur[d >> 8], 1);
    pairs[pos] = (sv << 8) | (d & 255u);
  }
  __syncthreads();
}

static __device__ __forceinline__ void dev_csr(int k, int tid, int* s,
    int* bofs, int* cnt, int* sc, const unsigned* __restrict__ pairs,
    const int* __restrict__ total, int* __restrict__ rowptr,
    int* __restrict__ srcs) {
  {
    const int v = (tid < NBK) ? total[tid] : 0;
    s[tid] = v;
    __syncthreads();
    for (int off = 1; off < 256; off <<= 1) {
      const int u = (tid >= off) ? s[tid - off] : 0;
      __syncthreads();
      s[tid] += u;
      __syncthreads();
    }
    if (tid < NBK) bofs[tid] = s[tid] - v;
  }
  __syncthreads();

  const int base = bofs[k];
  const int limit = base + total[k];

  cnt[tid] = 0;
  __syncthreads();
  for (int i = base + tid; i < limit; i += 256)
    atomicAdd(&cnt[pairs[i] & 255u], 1);
  __syncthreads();

  const int v = cnt[tid];
  sc[tid] = v;
  __syncthreads();
  for (int off = 1; off < 256; off <<= 1) {
    const int u = (tid >= off) ? sc[tid - off] : 0;
    __syncthreads();
    sc[tid] += u;
    __syncthreads();
  }
  const int ex = base + sc[tid] - v;  // exclusive global position

  const int node = k * 256 + tid;
  if (node < N_NODES) rowptr[node] = ex;
  if (k == 0 && tid == 0) rowptr[N_NODES] = N_EDGES;

  cnt[tid] = ex;  // reuse as cursor
  __syncthreads();
  for (int i = base + tid; i < limit; i += 256) {
    const unsigned p = pairs[i];
    const int pos = atomicAdd(&cnt[p & 255u], 1);
    srcs[pos] = (int)(p >> 8);
  }
  __syncthreads();
}

static __device__ __forceinline__ void dev_gather(int task, int tid,
    const unsigned short* __restrict__ hin, const int* __restrict__ rowptr,
    const int* __restrict__ srcs, unsigned short* __restrict__ hout) {
  const int node = task * 4 + (tid >> 6);  // always < N_NODES (exact tiling)
  const int lane = tid & 63;
  const int g = lane >> 3;
  const int sl = lane & 7;

  const int beg = rowptr[node];
  const int end = rowptr[node + 1];

  float acc[8];
#pragma unroll
  for (int j = 0; j < 8; ++j) acc[j] = 0.0f;

  for (int i = beg + g; i < end; i += 8) {
    const int src = srcs[i];
    const uint4 v = *reinterpret_cast<const uint4*>(
        hin + (size_t)src * IN_CH + sl * 8);
    acc[0] += bf2f(v.x & 0xffffu); acc[1] += bf2f(v.x >> 16);
    acc[2] += bf2f(v.y & 0xffffu); acc[3] += bf2f(v.y >> 16);
    acc[4] += bf2f(v.z & 0xffffu); acc[5] += bf2f(v.z >> 16);
    acc[6] += bf2f(v.w & 0xffffu); acc[7] += bf2f(v.w >> 16);
  }

#pragma unroll
  for (int j = 0; j < 8; ++j) {
    acc[j] += __shfl_xor(acc[j], 8);
    acc[j] += __shfl_xor(acc[j], 16);
    acc[j] += __shfl_xor(acc[j], 32);
  }

  if (g == 0) {
    union { unsigned u[4]; uint4 v; } o;
    o.u[0] = (unsigned)f2bf(acc[0]) | ((unsigned)f2bf(acc[1]) << 16);
    o.u[1] = (unsigned)f2bf(acc[2]) | ((unsigned)f2bf(acc[3]) << 16);
    o.u[2] = (unsigned)f2bf(acc[4]) | ((unsigned)f2bf(acc[5]) << 16);
    o.u[3] = (unsigned)f2bf(acc[6]) | ((unsigned)f2bf(acc[7]) << 16);
    *reinterpret_cast<uint4*>(hout + (size_t)node * IN_CH + sl * 8) = o.v;
  }
}

static __device__ __forceinline__ void dev_gemm(int task, int tid,
    const unsigned short* __restrict__ xb,
    const unsigned short* __restrict__ h1b,
    const unsigned short* __restrict__ h2b,
    const unsigned short* __restrict__ Wf, const float* __restrict__ bvec,
    float* __restrict__ out) {
  const int wave = task * 4 + (tid >> 6);
  if (wave >= N_TILES) return;
  const int lane = tid & 63;
  const int node0 = wave * 16;
  const int mrow = lane & 15;
  const int kg = lane >> 4;

  f32x4 acc[8];
#pragma unroll
  for (int nt = 0; nt < 8; ++nt) acc[nt] = (f32x4){0.f, 0.f, 0.f, 0.f};

  const unsigned short* const srcarr[3] = {xb, h1b, h2b};
#pragma unroll
  for (int kk = 0; kk < 6; ++kk) {
    const unsigned short* a = srcarr[kk >> 1];
    const short8 af = *reinterpret_cast<const short8*>(
        a + (size_t)(node0 + mrow) * IN_CH + (kk & 1) * 32 + kg * 8);
#pragma unroll
    for (int nt = 0; nt < 8; ++nt) {
      const short8 bf = *reinterpret_cast<const short8*>(
          Wf + ((size_t)(kk * 8 + nt) * 64 + lane) * 8);
      acc[nt] =
          __builtin_amdgcn_mfma_f32_16x16x32_bf16(af, bf, acc[nt], 0, 0, 0);
    }
  }

#pragma unroll
  for (int nt = 0; nt < 8; ++nt) {
    const int oc = nt * 16 + mrow;
    const float bias = bvec[oc];
#pragma unroll
    for (int r = 0; r < 4; ++r) {
      out[(size_t)(node0 + kg * 4 + r) * OUT_CH + oc] = acc[nt][r] + bias;
    }
  }
}

// ===========================================================================
// Fused cooperative kernel: 7 phases, 6 grid.sync()s.
// ===========================================================================
__global__ __launch_bounds__(256, 2) void fused_kernel(
    const int* __restrict__ ei, const float* __restrict__ x,
    const float* __restrict__ W, const float* __restrict__ bvec,
    float* __restrict__ out, int* __restrict__ hist_t,
    int* __restrict__ offs_t, int* __restrict__ total,
    int* __restrict__ rowptr, unsigned* __restrict__ pairs,
    int* __restrict__ srcs, unsigned short* __restrict__ xb,
    unsigned short* __restrict__ h1b, unsigned short* __restrict__ h2b,
    unsigned short* __restrict__ Wf) {
  cg::grid_group grid = cg::this_grid();
  __shared__ int smem[1024];
  const int bid = blockIdx.x;
  const int tid = threadIdx.x;

  for (int t = bid; t < NPB + CAST_TASKS + WFRAG_TASKS; t += GRID) {
    if (t < NPB) dev_hist(t, tid, smem, ei, hist_t);
    else if (t < NPB + CAST_TASKS) dev_cast((t - NPB) * 256 + tid, x, xb);
    else dev_wfrag((t - NPB - CAST_TASKS) * 256 + tid, W, Wf);
  }
  grid.sync();
  for (int k = bid; k < NBK; k += GRID)
    dev_scan(k, tid, smem, hist_t, offs_t, total);
  grid.sync();
  for (int b2 = bid; b2 < NPB; b2 += GRID)
    dev_fill(b2, tid, smem, smem + 256, ei, total, offs_t, pairs);
  grid.sync();
  for (int k = bid; k < NBK; k += GRID)
    dev_csr(k, tid, smem, smem + 256, smem + 452, smem + 708, pairs, total,
            rowptr, srcs);
  grid.sync();
  for (int t = bid; t < GATHER_TASKS; t += GRID)
    dev_gather(t, tid, xb, rowptr, srcs, h1b);
  grid.sync();
  for (int t = bid; t < GATHER_TASKS; t += GRID)
    dev_gather(t, tid, h1b, rowptr, srcs, h2b);
  grid.sync();
  for (int t = bid; t < GEMM_TASKS; t += GRID)
    dev_gemm(t, tid, xb, h1b, h2b, Wf, bvec, out);
}

// ===========================================================================
// Standalone fallback kernels (round-11-proven pipeline).
// ===========================================================================
__global__ __launch_bounds__(256) void k_hist_prep(
    const int* __restrict__ ei, const float* __restrict__ x,
    const float* __restrict__ W, int* __restrict__ hist_t,
    unsigned short* __restrict__ xb, unsigned short* __restrict__ Wf) {
  __shared__ int lh[NBK];
  const int t = blockIdx.x;
  if (t < NPB) dev_hist(t, threadIdx.x, lh, ei, hist_t);
  else if (t < NPB + CAST_TASKS) dev_cast((t - NPB) * 256 + threadIdx.x, x, xb);
  else dev_wfrag((t - NPB - CAST_TASKS) * 256 + threadIdx.x, W, Wf);
}

__global__ __launch_bounds__(256) void k_scan(const int* __restrict__ hist_t,
                                              int* __restrict__ offs_t,
                                              int* __restrict__ total) {
  __shared__ int s[256];
  dev_scan(blockIdx.x, threadIdx.x, s, hist_t, offs_t, total);
}

__global__ __launch_bounds__(256) void k_fill(const int* __restrict__ ei,
                                              const int* __restrict__ total,
                                              const int* __restrict__ offs_t,
                                              unsigned* __restrict__ pairs) {
  __shared__ int s[256];
  __shared__ int cur[NBK];
  dev_fill(blockIdx.x, threadIdx.x, s, cur, ei, total, offs_t, pairs);
}

__global__ __launch_bounds__(256) void k_csr(const unsigned* __restrict__ pairs,
                                             const int* __restrict__ total,
                                             int* __restrict__ rowptr,
                                             int* __restrict__ srcs) {
  __shared__ int s[256];
  __shared__ int bofs[NBK];
  __shared__ int cnt[256];
  __shared__ int sc[256];
  dev_csr(blockIdx.x, threadIdx.x, s, bofs, cnt, sc, pairs, total, rowptr,
          srcs);
}

__global__ __launch_bounds__(256) void k_gather(
    const unsigned short* __restrict__ hin, const int* __restrict__ rowptr,
    const int* __restrict__ srcs, unsigned short* __restrict__ hout) {
  dev_gather(blockIdx.x, threadIdx.x, hin, rowptr, srcs, hout);
}

__global__ __launch_bounds__(256) void k_gemm(
    const unsigned short* __restrict__ xb,
    const unsigned short* __restrict__ h1b,
    const unsigned short* __restrict__ h2b,
    const unsigned short* __restrict__ Wf, const float* __restrict__ bvec,
    float* __restrict__ out) {
  dev_gemm(blockIdx.x, threadIdx.x, xb, h1b, h2b, Wf, bvec, out);
}

extern "C" void kernel_launch(void* const* d_in, const int* in_sizes, int n_in,
                              void* d_out, int out_size, void* d_ws,
                              size_t ws_size, hipStream_t stream) {
  const float* x = (const float*)d_in[0];
  const int* ei = (const int*)d_in[1];   // [2, N_EDGES], int32 per harness
  const float* W = (const float*)d_in[2];
  const float* b = (const float*)d_in[3];
  float* out = (float*)d_out;

  char* p = (char*)d_ws;
  auto take = [&](size_t bytes) {
    char* r = p;
    p += (bytes + 255) & ~(size_t)255;
    return r;
  };
  unsigned short* xb  = (unsigned short*)take((size_t)N_NODES * IN_CH * 2);
  unsigned short* h1b = (unsigned short*)take((size_t)N_NODES * IN_CH * 2);
  unsigned short* h2b = (unsigned short*)take((size_t)N_NODES * IN_CH * 2);
  unsigned short* Wf  = (unsigned short*)take((size_t)FEAT * OUT_CH * 2);
  int* total  = (int*)take((size_t)NBK * 4);
  int* rowptr = (int*)take((size_t)(N_NODES + 1) * 4);
  unsigned* pairs = (unsigned*)take((size_t)N_EDGES * 4);
  int* srcs   = (int*)take((size_t)N_EDGES * 4);
  int* hist_t = (int*)take((size_t)NBK * NPB * 4);
  int* offs_t = (int*)take((size_t)NBK * NPB * 4);

  void* args[] = {(void*)&ei,     (void*)&x,      (void*)&W,
                  (void*)&b,      (void*)&out,    (void*)&hist_t,
                  (void*)&offs_t, (void*)&total,  (void*)&rowptr,
                  (void*)&pairs,  (void*)&srcs,   (void*)&xb,
                  (void*)&h1b,    (void*)&h2b,    (void*)&Wf};
  hipError_t cerr = hipLaunchCooperativeKernel(
      (const void*)fused_kernel, dim3(GRID), dim3(256), args, 0, stream);
  if (cerr != hipSuccess) {
    (void)hipGetLastError();  // clear sticky error; deterministic every call
    k_hist_prep<<<NPB + CAST_TASKS + WFRAG_TASKS, 256, 0, stream>>>(
        ei, x, W, hist_t, xb, Wf);
    k_scan<<<NBK, 256, 0, stream>>>(hist_t, offs_t, total);
    k_fill<<<NPB, 256, 0, stream>>>(ei, total, offs_t, pairs);
    k_csr<<<NBK, 256, 0, stream>>>(pairs, total, rowptr, srcs);
    k_gather<<<GATHER_TASKS, 256, 0, stream>>>(xb, rowptr, srcs, h1b);
    k_gather<<<GATHER_TASKS, 256, 0, stream>>>(h1b, rowptr, srcs, h2b);
    k_gemm<<<GEMM_TASKS, 256, 0, stream>>>(xb, h1b, h2b, Wf, b, out);
  }
}

// Round 14
// 161.701 us; speedup vs baseline: 3.5132x; 3.5132x over previous
//
#include <hip/hip_runtime.h>

#define N_NODES 50000
#define N_EDGES 800000
#define IN_CH   64
#define OUT_CH  128
#define FEAT    192                          // IN_CH * 3 powers
#define NBK     ((N_NODES + 255) / 256)      // 196 dst-buckets of 256 nodes
#define EPB     4096                         // edges per partition chunk
#define NPB     ((N_EDGES + EPB - 1) / EPB)  // 196 edge-chunks
#define N_TILES (N_NODES / 16)               // 3125 16-node tiles
#define CAST_TASKS  ((N_NODES * IN_CH / 8 + 255) / 256)   // 1563
#define WFRAG_TASKS ((FEAT * OUT_CH + 255) / 256)         // 96
#define GATHER_TASKS ((N_NODES * 64) / 256)               // 12500 (exact)

typedef __attribute__((ext_vector_type(8))) short short8;  // 8 bf16 (4 VGPRs)
typedef __attribute__((ext_vector_type(4))) float f32x4;

static __device__ __forceinline__ unsigned short f2bf(float f) {
  unsigned int u = __float_as_uint(f);
  u += 0x7FFFu + ((u >> 16) & 1u);
  return (unsigned short)(u >> 16);
}
static __device__ __forceinline__ float bf2f(unsigned int s) {
  return __uint_as_float(s << 16);
}

// ===========================================================================
// Shared phase bodies (round-11-proven).
// ===========================================================================

static __device__ __forceinline__ void dev_hist(int b, int tid, int* lh,
    const int* __restrict__ ei, int* __restrict__ hist_t) {
  for (int i = tid; i < NBK; i += 256) lh[i] = 0;
  __syncthreads();
  const int e0 = b * EPB;
  const int e1 = (e0 + EPB < N_EDGES) ? e0 + EPB : N_EDGES;
  for (int e = e0 + tid; e < e1; e += 256)
    atomicAdd(&lh[((unsigned)ei[N_EDGES + e]) >> 8], 1);
  __syncthreads();
  for (int k = tid; k < NBK; k += 256) hist_t[k * NPB + b] = lh[k];
}

static __device__ __forceinline__ void dev_cast(int i,
    const float* __restrict__ x, unsigned short* __restrict__ xb) {
  if (i >= (N_NODES * IN_CH) / 8) return;
  const float4 a = reinterpret_cast<const float4*>(x)[i * 2];
  const float4 c = reinterpret_cast<const float4*>(x)[i * 2 + 1];
  union { unsigned u[4]; uint4 v; } o;
  o.u[0] = (unsigned)f2bf(a.x) | ((unsigned)f2bf(a.y) << 16);
  o.u[1] = (unsigned)f2bf(a.z) | ((unsigned)f2bf(a.w) << 16);
  o.u[2] = (unsigned)f2bf(c.x) | ((unsigned)f2bf(c.y) << 16);
  o.u[3] = (unsigned)f2bf(c.z) | ((unsigned)f2bf(c.w) << 16);
  reinterpret_cast<uint4*>(xb)[i] = o.v;
}

static __device__ __forceinline__ void dev_wfrag(int i,
    const float* __restrict__ W, unsigned short* __restrict__ Wf) {
  if (i >= FEAT * OUT_CH) return;
  const int j = i & 7;
  const int l = (i >> 3) & 63;
  const int nt = (i >> 9) & 7;
  const int kk = i >> 12;
  const int o = nt * 16 + (l & 15);
  const int k = kk * 32 + (l >> 4) * 8 + j;
  Wf[i] = f2bf(W[o * FEAT + k]);
}

static __device__ __forceinline__ void dev_scan(int k, int tid, int* s,
    const int* __restrict__ hist_t, int* __restrict__ offs_t,
    int* __restrict__ total) {
  const int v = (tid < NPB) ? hist_t[k * NPB + tid] : 0;
  s[tid] = v;
  __syncthreads();
  for (int off = 1; off < 256; off <<= 1) {
    const int u = (tid >= off) ? s[tid - off] : 0;
    __syncthreads();
    s[tid] += u;
    __syncthreads();
  }
  if (tid < NPB) offs_t[k * NPB + tid] = s[tid] - v;  // exclusive
  if (tid == 255) total[k] = s[255];
}

static __device__ __forceinline__ void dev_fill(int b, int tid, int* s,
    int* cur, const int* __restrict__ ei, const int* __restrict__ total,
    const int* __restrict__ offs_t, unsigned* __restrict__ pairs) {
  const int v = (tid < NBK) ? total[tid] : 0;
  s[tid] = v;
  __syncthreads();
  for (int off = 1; off < 256; off <<= 1) {
    const int u = (tid >= off) ? s[tid - off] : 0;
    __syncthreads();
    s[tid] += u;
    __syncthreads();
  }
  if (tid < NBK) cur[tid] = (s[tid] - v) + offs_t[tid * NPB + b];
  __syncthreads();
  const int e0 = b * EPB;
  const int e1 = (e0 + EPB < N_EDGES) ? e0 + EPB : N_EDGES;
  for (int e = e0 + tid; e < e1; e += 256) {
    const unsigned sv = (unsigned)ei[e];
    const unsigned d = (unsigned)ei[N_EDGES + e];
    const int pos = atomicAdd(&cur[d >> 8], 1);
    pairs[pos] = (sv << 8) | (d & 255u);
  }
}

static __device__ __forceinline__ void dev_csr(int k, int tid, int* s,
    int* bofs, int* cnt, int* sc, const unsigned* __restrict__ pairs,
    const int* __restrict__ total, int* __restrict__ rowptr,
    int* __restrict__ srcs) {
  {
    const int v = (tid < NBK) ? total[tid] : 0;
    s[tid] = v;
    __syncthreads();
    for (int off = 1; off < 256; off <<= 1) {
      const int u = (tid >= off) ? s[tid - off] : 0;
      __syncthreads();
      s[tid] += u;
      __syncthreads();
    }
    if (tid < NBK) bofs[tid] = s[tid] - v;
  }
  __syncthreads();

  const int base = bofs[k];
  const int limit = base + total[k];

  cnt[tid] = 0;
  __syncthreads();
  for (int i = base + tid; i < limit; i += 256)
    atomicAdd(&cnt[pairs[i] & 255u], 1);
  __syncthreads();

  const int v = cnt[tid];
  sc[tid] = v;
  __syncthreads();
  for (int off = 1; off < 256; off <<= 1) {
    const int u = (tid >= off) ? sc[tid - off] : 0;
    __syncthreads();
    sc[tid] += u;
    __syncthreads();
  }
  const int ex = base + sc[tid] - v;  // exclusive global position

  const int node = k * 256 + tid;
  if (node < N_NODES) rowptr[node] = ex;
  if (k == 0 && tid == 0) rowptr[N_NODES] = N_EDGES;

  cnt[tid] = ex;  // reuse as cursor
  __syncthreads();
  for (int i = base + tid; i < limit; i += 256) {
    const unsigned p = pairs[i];
    const int pos = atomicAdd(&cnt[p & 255u], 1);
    srcs[pos] = (int)(p >> 8);
  }
}

// Gather one node's row: returns packed bf16 row slice (4 u32 = 8 channels
// at sl*8) valid on lanes with g==0. All 64 lanes of the wave participate.
static __device__ __forceinline__ uint4 gather_row(int node, int lane,
    const unsigned short* __restrict__ hin, const int* __restrict__ rowptr,
    const int* __restrict__ srcs) {
  const int g = lane >> 3;
  const int sl = lane & 7;
  const int beg = rowptr[node];
  const int end = rowptr[node + 1];

  float acc[8];
#pragma unroll
  for (int j = 0; j < 8; ++j) acc[j] = 0.0f;

  for (int i = beg + g; i < end; i += 8) {
    const int src = srcs[i];
    const uint4 v = *reinterpret_cast<const uint4*>(
        hin + (size_t)src * IN_CH + sl * 8);
    acc[0] += bf2f(v.x & 0xffffu); acc[1] += bf2f(v.x >> 16);
    acc[2] += bf2f(v.y & 0xffffu); acc[3] += bf2f(v.y >> 16);
    acc[4] += bf2f(v.z & 0xffffu); acc[5] += bf2f(v.z >> 16);
    acc[6] += bf2f(v.w & 0xffffu); acc[7] += bf2f(v.w >> 16);
  }

#pragma unroll
  for (int j = 0; j < 8; ++j) {
    acc[j] += __shfl_xor(acc[j], 8);
    acc[j] += __shfl_xor(acc[j], 16);
    acc[j] += __shfl_xor(acc[j], 32);
  }

  union { unsigned u[4]; uint4 v; } o;
  o.u[0] = (unsigned)f2bf(acc[0]) | ((unsigned)f2bf(acc[1]) << 16);
  o.u[1] = (unsigned)f2bf(acc[2]) | ((unsigned)f2bf(acc[3]) << 16);
  o.u[2] = (unsigned)f2bf(acc[4]) | ((unsigned)f2bf(acc[5]) << 16);
  o.u[3] = (unsigned)f2bf(acc[6]) | ((unsigned)f2bf(acc[7]) << 16);
  return o.v;
}

// ===========================================================================
// Dispatch 1: dst-bucket histograms (transposed).
// ===========================================================================
__global__ __launch_bounds__(256) void k_hist(const int* __restrict__ ei,
                                              int* __restrict__ hist_t) {
  __shared__ int lh[NBK];
  dev_hist(blockIdx.x, threadIdx.x, lh, ei, hist_t);
}

// ===========================================================================
// Dispatch 2: blocks [0,NBK) per-bucket scan; then cast x; then wfrag W.
// ===========================================================================
__global__ __launch_bounds__(256) void k_scanprep(
    const int* __restrict__ hist_t, int* __restrict__ offs_t,
    int* __restrict__ total, const float* __restrict__ x,
    const float* __restrict__ W, unsigned short* __restrict__ xb,
    unsigned short* __restrict__ Wf) {
  __shared__ int s[256];
  const int t = blockIdx.x;
  if (t < NBK) dev_scan(t, threadIdx.x, s, hist_t, offs_t, total);
  else if (t < NBK + CAST_TASKS)
    dev_cast((t - NBK) * 256 + threadIdx.x, x, xb);
  else
    dev_wfrag((t - NBK - CAST_TASKS) * 256 + threadIdx.x, W, Wf);
}

// ===========================================================================
// Dispatch 3: deterministic bucket fill.
// ===========================================================================
__global__ __launch_bounds__(256) void k_fill(const int* __restrict__ ei,
                                              const int* __restrict__ total,
                                              const int* __restrict__ offs_t,
                                              unsigned* __restrict__ pairs) {
  __shared__ int s[256];
  __shared__ int cur[NBK];
  dev_fill(blockIdx.x, threadIdx.x, s, cur, ei, total, offs_t, pairs);
}

// ===========================================================================
// Dispatch 4: per-bucket local CSR -> rowptr, srcs.
// ===========================================================================
__global__ __launch_bounds__(256) void k_csr(const unsigned* __restrict__ pairs,
                                             const int* __restrict__ total,
                                             int* __restrict__ rowptr,
                                             int* __restrict__ srcs) {
  __shared__ int s[256];
  __shared__ int bofs[NBK];
  __shared__ int cnt[256];
  __shared__ int sc[256];
  dev_csr(blockIdx.x, threadIdx.x, s, bofs, cnt, sc, pairs, total, rowptr,
          srcs);
}

// ===========================================================================
// Dispatch 5: gather hop 1 (h1 = A*x), one wave per node, write global.
// ===========================================================================
__global__ __launch_bounds__(256) void k_gather(
    const unsigned short* __restrict__ hin, const int* __restrict__ rowptr,
    const int* __restrict__ srcs, unsigned short* __restrict__ hout) {
  const int node = blockIdx.x * 4 + (threadIdx.x >> 6);  // exact tiling
  const int lane = threadIdx.x & 63;
  const uint4 o = gather_row(node, lane, hin, rowptr, srcs);
  if ((lane >> 3) == 0) {
    *reinterpret_cast<uint4*>(
        hout + (size_t)node * IN_CH + (lane & 7) * 8) = o;
  }
}

// ===========================================================================
// Dispatch 6: fused hop 2 + GEMM. Block = 16 nodes, 4 waves.
//  - each wave gathers 4 h2 rows (h2 = A*h1) into LDS sfu[16][40] dwords
//    (160 B row stride: conflict-free writes, <=4-way ds_read_b128 reads)
//  - __syncthreads
//  - 16-node MFMA tile split across waves: wave w does n-tiles {2w, 2w+1}
//    (12 MFMA each). A-frags: xb/h1b from global, h2 from LDS.
// C/D layout (m89-verified): D[(l>>4)*4+r][l&15].
// ===========================================================================
__global__ __launch_bounds__(256) void k_g2gemm(
    const unsigned short* __restrict__ xb,
    const unsigned short* __restrict__ h1b, const int* __restrict__ rowptr,
    const int* __restrict__ srcs, const unsigned short* __restrict__ Wf,
    const float* __restrict__ bvec, float* __restrict__ out) {
  __shared__ unsigned sfu[16 * 40];  // [16 nodes][40 dwords] (32 used + pad)
  const int tid = threadIdx.x;
  const int w = tid >> 6;
  const int lane = tid & 63;
  const int node0 = blockIdx.x * 16;

  // ---- hop 2: gather this block's 16 h2 rows into LDS ----
#pragma unroll
  for (int j = 0; j < 4; ++j) {
    const int ln = w * 4 + j;
    const uint4 o = gather_row(node0 + ln, lane, h1b, rowptr, srcs);
    if ((lane >> 3) == 0) {
      *reinterpret_cast<uint4*>(&sfu[ln * 40 + (lane & 7) * 4]) = o;
    }
  }
  __syncthreads();

  // ---- GEMM for the 16-node tile, 2 n-tiles per wave ----
  const int mrow = lane & 15;
  const int kg = lane >> 4;

  f32x4 acc[2];
  acc[0] = (f32x4){0.f, 0.f, 0.f, 0.f};
  acc[1] = (f32x4){0.f, 0.f, 0.f, 0.f};

#pragma unroll
  for (int kk = 0; kk < 6; ++kk) {
    short8 af;
    if (kk < 4) {
      const unsigned short* a = (kk < 2) ? xb : h1b;
      af = *reinterpret_cast<const short8*>(
          a + (size_t)(node0 + mrow) * IN_CH + (kk & 1) * 32 + kg * 8);
    } else {
      af = *reinterpret_cast<const short8*>(
          &sfu[mrow * 40 + (kk & 1) * 16 + kg * 4]);
    }
#pragma unroll
    for (int q = 0; q < 2; ++q) {
      const int nt = 2 * w + q;
      const short8 bf = *reinterpret_cast<const short8*>(
          Wf + ((size_t)(kk * 8 + nt) * 64 + lane) * 8);
      acc[q] =
          __builtin_amdgcn_mfma_f32_16x16x32_bf16(af, bf, acc[q], 0, 0, 0);
    }
  }

#pragma unroll
  for (int q = 0; q < 2; ++q) {
    const int nt = 2 * w + q;
    const int oc = nt * 16 + mrow;
    const float bias = bvec[oc];
#pragma unroll
    for (int r = 0; r < 4; ++r) {
      out[(size_t)(node0 + kg * 4 + r) * OUT_CH + oc] = acc[q][r] + bias;
    }
  }
}

extern "C" void kernel_launch(void* const* d_in, const int* in_sizes, int n_in,
                              void* d_out, int out_size, void* d_ws,
                              size_t ws_size, hipStream_t stream) {
  const float* x = (const float*)d_in[0];
  const int* ei = (const int*)d_in[1];   // [2, N_EDGES], int32 per harness
  const float* W = (const float*)d_in[2];
  const float* b = (const float*)d_in[3];
  float* out = (float*)d_out;

  char* p = (char*)d_ws;
  auto take = [&](size_t bytes) {
    char* r = p;
    p += (bytes + 255) & ~(size_t)255;
    return r;
  };
  unsigned short* xb  = (unsigned short*)take((size_t)N_NODES * IN_CH * 2);
  unsigned short* h1b = (unsigned short*)take((size_t)N_NODES * IN_CH * 2);
  unsigned short* Wf  = (unsigned short*)take((size_t)FEAT * OUT_CH * 2);
  int* total  = (int*)take((size_t)NBK * 4);
  int* rowptr = (int*)take((size_t)(N_NODES + 1) * 4);
  unsigned* pairs = (unsigned*)take((size_t)N_EDGES * 4);
  int* srcs   = (int*)take((size_t)N_EDGES * 4);
  int* hist_t = (int*)take((size_t)NBK * NPB * 4);
  int* offs_t = (int*)take((size_t)NBK * NPB * 4);

  // 1) dst-bucket histogram per edge-chunk (transposed table)
  k_hist<<<NPB, 256, 0, stream>>>(ei, hist_t);
  // 2) per-bucket scan + x cast + W fragment shuffle (one dispatch)
  k_scanprep<<<NBK + CAST_TASKS + WFRAG_TASKS, 256, 0, stream>>>(
      hist_t, offs_t, total, x, W, xb, Wf);
  // 3) deterministic bucket-grouped fill
  k_fill<<<NPB, 256, 0, stream>>>(ei, total, offs_t, pairs);
  // 4) per-bucket local CSR
  k_csr<<<NBK, 256, 0, stream>>>(pairs, total, rowptr, srcs);
  // 5) hop 1: h1 = A*x
  k_gather<<<GATHER_TASKS, 256, 0, stream>>>(xb, rowptr, srcs, h1b);
  // 6) hop 2 fused with GEMM (h2 lives only in LDS)
  k_g2gemm<<<N_TILES, 256, 0, stream>>>(xb, h1b, rowptr, srcs, Wf, b, out);
}

// Round 15
// 160.725 us; speedup vs baseline: 3.5345x; 1.0061x over previous
//
#include <hip/hip_runtime.h>

#define N_NODES 50000
#define N_EDGES 800000
#define IN_CH   64
#define OUT_CH  128
#define FEAT    192                          // IN_CH * 3 powers
#define NBK     ((N_NODES + 255) / 256)      // 196 dst-buckets of 256 nodes
#define EPB     4096                         // edges per partition chunk
#define NPB     ((N_EDGES + EPB - 1) / EPB)  // 196 edge-chunks
#define N_TILES (N_NODES / 16)               // 3125 16-node tiles
#define CAST_TASKS  ((N_NODES * IN_CH / 8 + 255) / 256)   // 1563
#define WFRAG_TASKS ((FEAT * OUT_CH + 255) / 256)         // 96
#define GATHER_TASKS ((N_NODES * 64) / 256)               // 12500 (exact)

typedef __attribute__((ext_vector_type(8))) short short8;  // 8 bf16 (4 VGPRs)
typedef __attribute__((ext_vector_type(4))) float f32x4;

static __device__ __forceinline__ unsigned short f2bf(float f) {
  unsigned int u = __float_as_uint(f);
  u += 0x7FFFu + ((u >> 16) & 1u);
  return (unsigned short)(u >> 16);
}
static __device__ __forceinline__ float bf2f(unsigned int s) {
  return __uint_as_float(s << 16);
}

// ===========================================================================
// Shared phase bodies (round-11/14-proven).
// ===========================================================================

static __device__ __forceinline__ void dev_hist(int b, int tid, int* lh,
    const int* __restrict__ ei, int* __restrict__ hist_t) {
  for (int i = tid; i < NBK; i += 256) lh[i] = 0;
  __syncthreads();
  const int e0 = b * EPB;
  const int e1 = (e0 + EPB < N_EDGES) ? e0 + EPB : N_EDGES;
  for (int e = e0 + tid; e < e1; e += 256)
    atomicAdd(&lh[((unsigned)ei[N_EDGES + e]) >> 8], 1);
  __syncthreads();
  for (int k = tid; k < NBK; k += 256) hist_t[k * NPB + b] = lh[k];
}

static __device__ __forceinline__ void dev_cast(int i,
    const float* __restrict__ x, unsigned short* __restrict__ xb) {
  if (i >= (N_NODES * IN_CH) / 8) return;
  const float4 a = reinterpret_cast<const float4*>(x)[i * 2];
  const float4 c = reinterpret_cast<const float4*>(x)[i * 2 + 1];
  union { unsigned u[4]; uint4 v; } o;
  o.u[0] = (unsigned)f2bf(a.x) | ((unsigned)f2bf(a.y) << 16);
  o.u[1] = (unsigned)f2bf(a.z) | ((unsigned)f2bf(a.w) << 16);
  o.u[2] = (unsigned)f2bf(c.x) | ((unsigned)f2bf(c.y) << 16);
  o.u[3] = (unsigned)f2bf(c.z) | ((unsigned)f2bf(c.w) << 16);
  reinterpret_cast<uint4*>(xb)[i] = o.v;
}

static __device__ __forceinline__ void dev_wfrag(int i,
    const float* __restrict__ W, unsigned short* __restrict__ Wf) {
  if (i >= FEAT * OUT_CH) return;
  const int j = i & 7;
  const int l = (i >> 3) & 63;
  const int nt = (i >> 9) & 7;
  const int kk = i >> 12;
  const int o = nt * 16 + (l & 15);
  const int k = kk * 32 + (l >> 4) * 8 + j;
  Wf[i] = f2bf(W[o * FEAT + k]);
}

static __device__ __forceinline__ void dev_scan(int k, int tid, int* s,
    const int* __restrict__ hist_t, int* __restrict__ offs_t,
    int* __restrict__ total) {
  const int v = (tid < NPB) ? hist_t[k * NPB + tid] : 0;
  s[tid] = v;
  __syncthreads();
  for (int off = 1; off < 256; off <<= 1) {
    const int u = (tid >= off) ? s[tid - off] : 0;
    __syncthreads();
    s[tid] += u;
    __syncthreads();
  }
  if (tid < NPB) offs_t[k * NPB + tid] = s[tid] - v;  // exclusive
  if (tid == 255) total[k] = s[255];
}

static __device__ __forceinline__ void dev_fill(int b, int tid, int* s,
    int* cur, const int* __restrict__ ei, const int* __restrict__ total,
    const int* __restrict__ offs_t, unsigned* __restrict__ pairs) {
  const int v = (tid < NBK) ? total[tid] : 0;
  s[tid] = v;
  __syncthreads();
  for (int off = 1; off < 256; off <<= 1) {
    const int u = (tid >= off) ? s[tid - off] : 0;
    __syncthreads();
    s[tid] += u;
    __syncthreads();
  }
  if (tid < NBK) cur[tid] = (s[tid] - v) + offs_t[tid * NPB + b];
  __syncthreads();
  const int e0 = b * EPB;
  const int e1 = (e0 + EPB < N_EDGES) ? e0 + EPB : N_EDGES;
  for (int e = e0 + tid; e < e1; e += 256) {
    const unsigned sv = (unsigned)ei[e];
    const unsigned d = (unsigned)ei[N_EDGES + e];
    const int pos = atomicAdd(&cur[d >> 8], 1);
    pairs[pos] = (sv << 8) | (d & 255u);
  }
}

static __device__ __forceinline__ void dev_csr(int k, int tid, int* s,
    int* bofs, int* cnt, int* sc, const unsigned* __restrict__ pairs,
    const int* __restrict__ total, int* __restrict__ rowptr,
    int* __restrict__ srcs) {
  {
    const int v = (tid < NBK) ? total[tid] : 0;
    s[tid] = v;
    __syncthreads();
    for (int off = 1; off < 256; off <<= 1) {
      const int u = (tid >= off) ? s[tid - off] : 0;
      __syncthreads();
      s[tid] += u;
      __syncthreads();
    }
    if (tid < NBK) bofs[tid] = s[tid] - v;
  }
  __syncthreads();

  const int base = bofs[k];
  const int limit = base + total[k];

  cnt[tid] = 0;
  __syncthreads();
  for (int i = base + tid; i < limit; i += 256)
    atomicAdd(&cnt[pairs[i] & 255u], 1);
  __syncthreads();

  const int v = cnt[tid];
  sc[tid] = v;
  __syncthreads();
  for (int off = 1; off < 256; off <<= 1) {
    const int u = (tid >= off) ? sc[tid - off] : 0;
    __syncthreads();
    sc[tid] += u;
    __syncthreads();
  }
  const int ex = base + sc[tid] - v;  // exclusive global position

  const int node = k * 256 + tid;
  if (node < N_NODES) rowptr[node] = ex;
  if (k == 0 && tid == 0) rowptr[N_NODES] = N_EDGES;

  cnt[tid] = ex;  // reuse as cursor
  __syncthreads();
  for (int i = base + tid; i < limit; i += 256) {
    const unsigned p = pairs[i];
    const int pos = atomicAdd(&cnt[p & 255u], 1);
    srcs[pos] = (int)(p >> 8);
  }
}

// ---------------------------------------------------------------------------
// Gather one node's row with a 2-deep software pipeline: two independent
// accumulator sets and two outstanding row loads per lane (slots i, i+8).
// The f32 acc chain is not compiler-reassociable, so without the manual
// unroll each lane has only 1 load in flight (latency-bound on random L3).
// Returns packed bf16 row slice (4 u32 = 8 ch at sl*8), valid where g==0.
// ---------------------------------------------------------------------------
static __device__ __forceinline__ uint4 gather_row(int node, int lane,
    const unsigned short* __restrict__ hin, const int* __restrict__ rowptr,
    const int* __restrict__ srcs) {
  const int g = lane >> 3;
  const int sl = lane & 7;
  const int beg = rowptr[node];
  const int end = rowptr[node + 1];

  float a0[8], a1[8];
#pragma unroll
  for (int j = 0; j < 8; ++j) { a0[j] = 0.0f; a1[j] = 0.0f; }

  int i = beg + g;
  for (; i + 8 < end; i += 16) {
    const int s0 = srcs[i];
    const int s1 = srcs[i + 8];
    const uint4 v0 = *reinterpret_cast<const uint4*>(
        hin + (size_t)s0 * IN_CH + sl * 8);
    const uint4 v1 = *reinterpret_cast<const uint4*>(
        hin + (size_t)s1 * IN_CH + sl * 8);
    a0[0] += bf2f(v0.x & 0xffffu); a0[1] += bf2f(v0.x >> 16);
    a0[2] += bf2f(v0.y & 0xffffu); a0[3] += bf2f(v0.y >> 16);
    a0[4] += bf2f(v0.z & 0xffffu); a0[5] += bf2f(v0.z >> 16);
    a0[6] += bf2f(v0.w & 0xffffu); a0[7] += bf2f(v0.w >> 16);
    a1[0] += bf2f(v1.x & 0xffffu); a1[1] += bf2f(v1.x >> 16);
    a1[2] += bf2f(v1.y & 0xffffu); a1[3] += bf2f(v1.y >> 16);
    a1[4] += bf2f(v1.z & 0xffffu); a1[5] += bf2f(v1.z >> 16);
    a1[6] += bf2f(v1.w & 0xffffu); a1[7] += bf2f(v1.w >> 16);
  }
  if (i < end) {
    const int s0 = srcs[i];
    const uint4 v0 = *reinterpret_cast<const uint4*>(
        hin + (size_t)s0 * IN_CH + sl * 8);
    a0[0] += bf2f(v0.x & 0xffffu); a0[1] += bf2f(v0.x >> 16);
    a0[2] += bf2f(v0.y & 0xffffu); a0[3] += bf2f(v0.y >> 16);
    a0[4] += bf2f(v0.z & 0xffffu); a0[5] += bf2f(v0.z >> 16);
    a0[6] += bf2f(v0.w & 0xffffu); a0[7] += bf2f(v0.w >> 16);
  }

#pragma unroll
  for (int j = 0; j < 8; ++j) {
    float a = a0[j] + a1[j];
    a += __shfl_xor(a, 8);
    a += __shfl_xor(a, 16);
    a += __shfl_xor(a, 32);
    a0[j] = a;
  }

  union { unsigned u[4]; uint4 v; } o;
  o.u[0] = (unsigned)f2bf(a0[0]) | ((unsigned)f2bf(a0[1]) << 16);
  o.u[1] = (unsigned)f2bf(a0[2]) | ((unsigned)f2bf(a0[3]) << 16);
  o.u[2] = (unsigned)f2bf(a0[4]) | ((unsigned)f2bf(a0[5]) << 16);
  o.u[3] = (unsigned)f2bf(a0[6]) | ((unsigned)f2bf(a0[7]) << 16);
  return o.v;
}

// ===========================================================================
// Dispatch 1: dst-bucket histograms (transposed).
// ===========================================================================
__global__ __launch_bounds__(256) void k_hist(const int* __restrict__ ei,
                                              int* __restrict__ hist_t) {
  __shared__ int lh[NBK];
  dev_hist(blockIdx.x, threadIdx.x, lh, ei, hist_t);
}

// ===========================================================================
// Dispatch 2: blocks [0,NBK) per-bucket scan; then cast x; then wfrag W.
// ===========================================================================
__global__ __launch_bounds__(256) void k_scanprep(
    const int* __restrict__ hist_t, int* __restrict__ offs_t,
    int* __restrict__ total, const float* __restrict__ x,
    const float* __restrict__ W, unsigned short* __restrict__ xb,
    unsigned short* __restrict__ Wf) {
  __shared__ int s[256];
  const int t = blockIdx.x;
  if (t < NBK) dev_scan(t, threadIdx.x, s, hist_t, offs_t, total);
  else if (t < NBK + CAST_TASKS)
    dev_cast((t - NBK) * 256 + threadIdx.x, x, xb);
  else
    dev_wfrag((t - NBK - CAST_TASKS) * 256 + threadIdx.x, W, Wf);
}

// ===========================================================================
// Dispatch 3: deterministic bucket fill.
// ===========================================================================
__global__ __launch_bounds__(256) void k_fill(const int* __restrict__ ei,
                                              const int* __restrict__ total,
                                              const int* __restrict__ offs_t,
                                              unsigned* __restrict__ pairs) {
  __shared__ int s[256];
  __shared__ int cur[NBK];
  dev_fill(blockIdx.x, threadIdx.x, s, cur, ei, total, offs_t, pairs);
}

// ===========================================================================
// Dispatch 4: per-bucket local CSR -> rowptr, srcs.
// ===========================================================================
__global__ __launch_bounds__(256) void k_csr(const unsigned* __restrict__ pairs,
                                             const int* __restrict__ total,
                                             int* __restrict__ rowptr,
                                             int* __restrict__ srcs) {
  __shared__ int s[256];
  __shared__ int bofs[NBK];
  __shared__ int cnt[256];
  __shared__ int sc[256];
  dev_csr(blockIdx.x, threadIdx.x, s, bofs, cnt, sc, pairs, total, rowptr,
          srcs);
}

// ===========================================================================
// Dispatch 5: gather hop 1 (h1 = A*x), one wave per node, write global.
// ===========================================================================
__global__ __launch_bounds__(256) void k_gather(
    const unsigned short* __restrict__ hin, const int* __restrict__ rowptr,
    const int* __restrict__ srcs, unsigned short* __restrict__ hout) {
  const int node = blockIdx.x * 4 + (threadIdx.x >> 6);  // exact tiling
  const int lane = threadIdx.x & 63;
  const uint4 o = gather_row(node, lane, hin, rowptr, srcs);
  if ((lane >> 3) == 0) {
    *reinterpret_cast<uint4*>(
        hout + (size_t)node * IN_CH + (lane & 7) * 8) = o;
  }
}

// ===========================================================================
// Dispatch 6: fused hop 2 + GEMM. Block = 16 nodes, 4 waves.
//  - each wave gathers 4 h2 rows (h2 = A*h1) into LDS sfu[16][40] dwords
//  - __syncthreads
//  - 16-node MFMA tile split across waves: wave w does n-tiles {2w, 2w+1}.
// C/D layout (m89-verified): D[(l>>4)*4+r][l&15].
// ===========================================================================
__global__ __launch_bounds__(256) void k_g2gemm(
    const unsigned short* __restrict__ xb,
    const unsigned short* __restrict__ h1b, const int* __restrict__ rowptr,
    const int* __restrict__ srcs, const unsigned short* __restrict__ Wf,
    const float* __restrict__ bvec, float* __restrict__ out) {
  __shared__ unsigned sfu[16 * 40];  // [16 nodes][40 dwords] (32 used + pad)
  const int tid = threadIdx.x;
  const int w = tid >> 6;
  const int lane = tid & 63;
  const int node0 = blockIdx.x * 16;

  // ---- hop 2: gather this block's 16 h2 rows into LDS ----
#pragma unroll
  for (int j = 0; j < 4; ++j) {
    const int ln = w * 4 + j;
    const uint4 o = gather_row(node0 + ln, lane, h1b, rowptr, srcs);
    if ((lane >> 3) == 0) {
      *reinterpret_cast<uint4*>(&sfu[ln * 40 + (lane & 7) * 4]) = o;
    }
  }
  __syncthreads();

  // ---- GEMM for the 16-node tile, 2 n-tiles per wave ----
  const int mrow = lane & 15;
  const int kg = lane >> 4;

  f32x4 acc[2];
  acc[0] = (f32x4){0.f, 0.f, 0.f, 0.f};
  acc[1] = (f32x4){0.f, 0.f, 0.f, 0.f};

#pragma unroll
  for (int kk = 0; kk < 6; ++kk) {
    short8 af;
    if (kk < 4) {
      const unsigned short* a = (kk < 2) ? xb : h1b;
      af = *reinterpret_cast<const short8*>(
          a + (size_t)(node0 + mrow) * IN_CH + (kk & 1) * 32 + kg * 8);
    } else {
      af = *reinterpret_cast<const short8*>(
          &sfu[mrow * 40 + (kk & 1) * 16 + kg * 4]);
    }
#pragma unroll
    for (int q = 0; q < 2; ++q) {
      const int nt = 2 * w + q;
      const short8 bf = *reinterpret_cast<const short8*>(
          Wf + ((size_t)(kk * 8 + nt) * 64 + lane) * 8);
      acc[q] =
          __builtin_amdgcn_mfma_f32_16x16x32_bf16(af, bf, acc[q], 0, 0, 0);
    }
  }

#pragma unroll
  for (int q = 0; q < 2; ++q) {
    const int nt = 2 * w + q;
    const int oc = nt * 16 + mrow;
    const float bias = bvec[oc];
#pragma unroll
    for (int r = 0; r < 4; ++r) {
      out[(size_t)(node0 + kg * 4 + r) * OUT_CH + oc] = acc[q][r] + bias;
    }
  }
}

extern "C" void kernel_launch(void* const* d_in, const int* in_sizes, int n_in,
                              void* d_out, int out_size, void* d_ws,
                              size_t ws_size, hipStream_t stream) {
  const float* x = (const float*)d_in[0];
  const int* ei = (const int*)d_in[1];   // [2, N_EDGES], int32 per harness
  const float* W = (const float*)d_in[2];
  const float* b = (const float*)d_in[3];
  float* out = (float*)d_out;

  char* p = (char*)d_ws;
  auto take = [&](size_t bytes) {
    char* r = p;
    p += (bytes + 255) & ~(size_t)255;
    return r;
  };
  unsigned short* xb  = (unsigned short*)take((size_t)N_NODES * IN_CH * 2);
  unsigned short* h1b = (unsigned short*)take((size_t)N_NODES * IN_CH * 2);
  unsigned short* Wf  = (unsigned short*)take((size_t)FEAT * OUT_CH * 2);
  int* total  = (int*)take((size_t)NBK * 4);
  int* rowptr = (int*)take((size_t)(N_NODES + 1) * 4);
  unsigned* pairs = (unsigned*)take((size_t)N_EDGES * 4);
  int* srcs   = (int*)take((size_t)N_EDGES * 4);
  int* hist_t = (int*)take((size_t)NBK * NPB * 4);
  int* offs_t = (int*)take((size_t)NBK * NPB * 4);

  // 1) dst-bucket histogram per edge-chunk (transposed table)
  k_hist<<<NPB, 256, 0, stream>>>(ei, hist_t);
  // 2) per-bucket scan + x cast + W fragment shuffle (one dispatch)
  k_scanprep<<<NBK + CAST_TASKS + WFRAG_TASKS, 256, 0, stream>>>(
      hist_t, offs_t, total, x, W, xb, Wf);
  // 3) deterministic bucket-grouped fill
  k_fill<<<NPB, 256, 0, stream>>>(ei, total, offs_t, pairs);
  // 4) per-bucket local CSR
  k_csr<<<NBK, 256, 0, stream>>>(pairs, total, rowptr, srcs);
  // 5) hop 1: h1 = A*x
  k_gather<<<GATHER_TASKS, 256, 0, stream>>>(xb, rowptr, srcs, h1b);
  // 6) hop 2 fused with GEMM (h2 lives only in LDS)
  k_g2gemm<<<N_TILES, 256, 0, stream>>>(xb, h1b, rowptr, srcs, Wf, b, out);
}